// Round 4
// baseline (448.764 us; speedup 1.0000x reference)
//
#include <hip/hip_runtime.h>

// Problem: B=1, S=I=H=4096. All tensors fp32 (inputs AND outputs).
// d_in: x(4096), hidden(4096), w_ih(12288*4096), w_hh(12288*4096),
//       b_ih(12288), b_hh(12288)
// d_out (fp32): outputs(4096*4096) ++ new_hidden(4096)
//
// Closed form of the reference scan:
//   g = [gi; gh] (24576 fp32) via GEMV
//   r = sig(gi_r+gh_r); z = sig(gi_z+gh_z); n = tanh(gi_n + r*gh_n)
//   a[s] = relu((1-z)*h + z*n)[s]
//   prefix[t] = inclusive_scan(a)[t]
//   outputs[t,j]  = prefix[t] + hidden[(j-t-1) & 4095]
//   new_hidden[j] = prefix[4095] + hidden[j]

#define H4 4096
#define R3 12288  // 3*H

// ---------------- Kernel 1: GEMV, LDS-staged vector ----------------------
// 16 rows per block (4 waves x 4 rows). Vector (x or hidden, 16 KB) staged
// into LDS once per block; weights are the only steady-state global traffic.
// blocks 0..767   : w_ih rows  block*16 .. +15      (vector = x)
// blocks 768..1535: w_hh rows (block-768)*16 .. +15 (vector = hidden)
__global__ __launch_bounds__(256) void gemv_kernel(
    const float* __restrict__ x,
    const float* __restrict__ hidden,
    const float* __restrict__ w_ih,
    const float* __restrict__ w_hh,
    const float* __restrict__ b_ih,
    const float* __restrict__ b_hh,
    float* __restrict__ g) {
  __shared__ float4 vs[1024];  // 16 KB

  const int block = blockIdx.x;
  const bool isX = (block < 768);
  const float* vec  = isX ? x    : hidden;
  const float* wmat = isX ? w_ih : w_hh;
  const float* bias = isX ? b_ih : b_hh;
  const int rowb = (isX ? block : block - 768) * 16;  // row within matrix
  const int gbase = isX ? 0 : R3;

  // Stage the 16 KB vector into LDS (coalesced, 4 float4 per thread).
  const float4* vv = reinterpret_cast<const float4*>(vec);
#pragma unroll
  for (int i = 0; i < 4; ++i) {
    const int idx = i * 256 + threadIdx.x;
    vs[idx] = vv[idx];
  }
  __syncthreads();

  const int wid = threadIdx.x >> 6;
  const int lane = threadIdx.x & 63;
  const int row0 = rowb + wid * 4;  // this wave's first row
  const float4* w0 = reinterpret_cast<const float4*>(wmat + (size_t)row0 * H4);

  float4 acc0 = {0.f, 0.f, 0.f, 0.f};
  float4 acc1 = {0.f, 0.f, 0.f, 0.f};
  float4 acc2 = {0.f, 0.f, 0.f, 0.f};
  float4 acc3 = {0.f, 0.f, 0.f, 0.f};

#pragma unroll
  for (int it = 0; it < 16; ++it) {
    const int idx = it * 64 + lane;  // float4 index within a row (1024/row)
    const float4 v4 = vs[idx];
    const float4 wq0 = w0[idx];
    const float4 wq1 = w0[1024 + idx];
    const float4 wq2 = w0[2048 + idx];
    const float4 wq3 = w0[3072 + idx];
    acc0.x = fmaf(wq0.x, v4.x, acc0.x); acc0.y = fmaf(wq0.y, v4.y, acc0.y);
    acc0.z = fmaf(wq0.z, v4.z, acc0.z); acc0.w = fmaf(wq0.w, v4.w, acc0.w);
    acc1.x = fmaf(wq1.x, v4.x, acc1.x); acc1.y = fmaf(wq1.y, v4.y, acc1.y);
    acc1.z = fmaf(wq1.z, v4.z, acc1.z); acc1.w = fmaf(wq1.w, v4.w, acc1.w);
    acc2.x = fmaf(wq2.x, v4.x, acc2.x); acc2.y = fmaf(wq2.y, v4.y, acc2.y);
    acc2.z = fmaf(wq2.z, v4.z, acc2.z); acc2.w = fmaf(wq2.w, v4.w, acc2.w);
    acc3.x = fmaf(wq3.x, v4.x, acc3.x); acc3.y = fmaf(wq3.y, v4.y, acc3.y);
    acc3.z = fmaf(wq3.z, v4.z, acc3.z); acc3.w = fmaf(wq3.w, v4.w, acc3.w);
  }

  float s0 = (acc0.x + acc0.y) + (acc0.z + acc0.w);
  float s1 = (acc1.x + acc1.y) + (acc1.z + acc1.w);
  float s2 = (acc2.x + acc2.y) + (acc2.z + acc2.w);
  float s3 = (acc3.x + acc3.y) + (acc3.z + acc3.w);
#pragma unroll
  for (int d = 32; d > 0; d >>= 1) {
    s0 += __shfl_down(s0, d, 64);
    s1 += __shfl_down(s1, d, 64);
    s2 += __shfl_down(s2, d, 64);
    s3 += __shfl_down(s3, d, 64);
  }
  if (lane == 0) {
    g[gbase + row0 + 0] = s0 + bias[row0 + 0];
    g[gbase + row0 + 1] = s1 + bias[row0 + 1];
    g[gbase + row0 + 2] = s2 + bias[row0 + 2];
    g[gbase + row0 + 3] = s3 + bias[row0 + 3];
  }
}

// -------- Kernel 2: GRU combine + block-wide inclusive scan (1 block) -----
__global__ __launch_bounds__(1024) void combine_scan_kernel(
    const float* __restrict__ hidden,
    const float* __restrict__ g,
    float* __restrict__ prefix,
    float* __restrict__ out_newh) {
  const int tid = threadIdx.x;
  const int s0 = tid * 4;

  const float4 gir = reinterpret_cast<const float4*>(g)[tid];
  const float4 giz = reinterpret_cast<const float4*>(g + H4)[tid];
  const float4 gin = reinterpret_cast<const float4*>(g + 2 * H4)[tid];
  const float4 ghr = reinterpret_cast<const float4*>(g + R3)[tid];
  const float4 ghz = reinterpret_cast<const float4*>(g + R3 + H4)[tid];
  const float4 ghn = reinterpret_cast<const float4*>(g + R3 + 2 * H4)[tid];
  const float4 h4v = reinterpret_cast<const float4*>(hidden)[tid];

  const float ir[4] = {gir.x, gir.y, gir.z, gir.w};
  const float iz[4] = {giz.x, giz.y, giz.z, giz.w};
  const float in_[4] = {gin.x, gin.y, gin.z, gin.w};
  const float hr[4] = {ghr.x, ghr.y, ghr.z, ghr.w};
  const float hz[4] = {ghz.x, ghz.y, ghz.z, ghz.w};
  const float hn[4] = {ghn.x, ghn.y, ghn.z, ghn.w};
  const float hh[4] = {h4v.x, h4v.y, h4v.z, h4v.w};

  float a[4];
#pragma unroll
  for (int k = 0; k < 4; ++k) {
    const float r = 1.f / (1.f + __expf(-(ir[k] + hr[k])));
    const float z = 1.f / (1.f + __expf(-(iz[k] + hz[k])));
    const float n = tanhf(in_[k] + r * hn[k]);
    const float b = (1.f - z) * hh[k] + z * n;
    a[k] = fmaxf(b, 0.f);
  }
  const float c0 = a[0], c1 = c0 + a[1], c2 = c1 + a[2], c3 = c2 + a[3];
  const float tsum = c3;

  const int lane = tid & 63, wid = tid >> 6;
  float v = tsum;
#pragma unroll
  for (int d = 1; d < 64; d <<= 1) {
    float o = __shfl_up(v, d, 64);
    if (lane >= d) v += o;
  }
  __shared__ float wsum[16];
  if (lane == 63) wsum[wid] = v;
  __syncthreads();
  if (tid < 16) {
    float w = wsum[tid];
#pragma unroll
    for (int d = 1; d < 16; d <<= 1) {
      float o = __shfl_up(w, d, 64);
      if (tid >= d) w += o;
    }
    wsum[tid] = w;
  }
  __syncthreads();

  const float excl = (wid ? wsum[wid - 1] : 0.f) + (v - tsum);
  float4 pr;
  pr.x = excl + c0; pr.y = excl + c1; pr.z = excl + c2; pr.w = excl + c3;
  reinterpret_cast<float4*>(prefix)[tid] = pr;

  const float total = wsum[15];
  float4 nh;
  nh.x = total + hh[0]; nh.y = total + hh[1];
  nh.z = total + hh[2]; nh.w = total + hh[3];
  reinterpret_cast<float4*>(out_newh)[tid] = nh;
}

// ------- Kernel 3: outputs[t,j] = prefix[t] + hidden[(j-t-1)&4095] --------
__global__ __launch_bounds__(256) void outputs_kernel(
    const float* __restrict__ prefix,
    const float* __restrict__ hidden,
    float* __restrict__ out) {
  const int b = blockIdx.x;
  const int t = b >> 1;
  const int j0 = (b & 1) * 2048 + threadIdx.x * 8;
  const float p = prefix[t];
  const int base = (j0 - t - 1) & 4095;

  float4 o0, o1;
  o0.x = p + hidden[base];
  o0.y = p + hidden[(base + 1) & 4095];
  o0.z = p + hidden[(base + 2) & 4095];
  o0.w = p + hidden[(base + 3) & 4095];
  o1.x = p + hidden[(base + 4) & 4095];
  o1.y = p + hidden[(base + 5) & 4095];
  o1.z = p + hidden[(base + 6) & 4095];
  o1.w = p + hidden[(base + 7) & 4095];

  float* dst = out + (size_t)t * H4 + j0;
  *reinterpret_cast<float4*>(dst)     = o0;
  *reinterpret_cast<float4*>(dst + 4) = o1;
}

extern "C" void kernel_launch(void* const* d_in, const int* in_sizes, int n_in,
                              void* d_out, int out_size, void* d_ws, size_t ws_size,
                              hipStream_t stream) {
  const float* x      = (const float*)d_in[0];
  const float* hidden = (const float*)d_in[1];
  const float* w_ih   = (const float*)d_in[2];
  const float* w_hh   = (const float*)d_in[3];
  const float* b_ih   = (const float*)d_in[4];
  const float* b_hh   = (const float*)d_in[5];
  float* out = (float*)d_out;

  float* ws     = (float*)d_ws;
  float* g      = ws;          // 24576 fp32
  float* prefix = ws + 24576;  // 4096 fp32

  // 24576 rows / 16 rows per block -> 1536 blocks (all co-resident)
  gemv_kernel<<<1536, 256, 0, stream>>>(x, hidden, w_ih, w_hh, b_ih, b_hh, g);
  combine_scan_kernel<<<1, 1024, 0, stream>>>(hidden, g, prefix,
                                              out + (size_t)H4 * H4);
  outputs_kernel<<<8192, 256, 0, stream>>>(prefix, hidden, out);
}